// Round 9
// baseline (99.742 us; speedup 1.0000x reference)
//
#include <hip/hip_runtime.h>

#define GRID_N 16384
#define NLAYERS 8
#define NPOS 32
#define BATCH 32
#define MW 4096          // output width
#define TILE 32
#define HALO 16          // 2 * NLAYERS
#define WBUF 64          // TILE + 2*HALO = one wave of column slots
#define ROWP 36          // gate row stride: 144B, 16B-aligned

typedef float f2 __attribute__((ext_vector_type(2)));

// DPP wave shifts: data from lane n-1 / n+1 (boundary lanes read 0; halo absorbs).
__device__ __forceinline__ float dpp_shr1(float v) {   // lane n <- lane n-1
    return __builtin_bit_cast(float, __builtin_amdgcn_update_dpp(
        0, __builtin_bit_cast(int, v), 0x138, 0xF, 0xF, true));
}
__device__ __forceinline__ float dpp_shl1(float v) {   // lane n <- lane n+1
    return __builtin_bit_cast(float, __builtin_amdgcn_update_dpp(
        0, __builtin_bit_cast(int, v), 0x130, 0xF, 0xF, true));
}
__device__ __forceinline__ f2 shr1(f2 v) { f2 r; r.x = dpp_shr1(v.x); r.y = dpp_shr1(v.y); return r; }
__device__ __forceinline__ f2 shl1(f2 v) { f2 r; r.x = dpp_shl1(v.x); r.y = dpp_shl1(v.y); return r; }

__device__ __forceinline__ float sigm(float v) {
    return __builtin_amdgcn_rcpf(1.0f + __expf(-v));
}

// v9 = MEASUREMENT PROBE. v8 body executed `reps`(=3) times inside one launch
// so the kernel's device time (~3*16us ~ 48us) crosses the rocprof top-5
// cutoff (~42.5us of harness poison fills) and we finally get REAL counters
// (VALUBusy / OccupancyPercent / SQ_LDS_BANK_CONFLICT / FETCH) for the
// DPP-register kernel family that has been invisible since R3.
// `reps` is a runtime arg + opaque rep-derived pointer offset -> compiler
// cannot collapse the rep loop; LDS staging + barriers repeat each rep.
// Output written identically every rep -> still exactly correct.
__global__ __launch_bounds__(512, 4) void ASIC_44186623541335_kernel(
    const float* __restrict__ x,    // (32, 4096)
    const float* __restrict__ tg,   // (8, 32, 16384) raw logits
    float* __restrict__ out,        // (32, 4096)
    int reps)
{
    __shared__ __align__(16) float twl[2][WBUF][ROWP];   // 18.4 KB, gates only

    const int tid = threadIdx.x;
    const int tx  = tid & 63;        // column slot (lane)
    const int w   = tid >> 6;        // wave 0..7 -> batches 4w..4w+3, gate cols 4w..4w+3
    const int c0  = 4 * w;
    const int start = blockIdx.x * TILE;
    const int gcol  = (start - HALO + tx) & (GRID_N - 1);

    for (int rep = 0; rep < reps; ++rep) {
        // runtime-zero, compile-time-opaque offset: defeats rep-loop collapsing
        const size_t ro = (size_t)((rep >> 8) & 1) * 4;
        const float* tgb = tg + ro;
        const float* xb  = x + ro;

        __syncthreads();   // rep boundary: twl reuse safe

        // ---- load gate logits for group 0 (layers 0,1) ----
        float pf[8];
        #pragma unroll
        for (int ll = 0; ll < 2; ++ll)
            #pragma unroll
            for (int k = 0; k < 4; ++k)
                pf[ll * 4 + k] = tgb[((size_t)ll * NPOS + c0 + k) * GRID_N + gcol];

        // ---- init state IN REGISTERS: embed x at stride 4, zeros elsewhere ----
        f2 S[2];
        {
            const bool on = (gcol & 3) == 0;
            const int  m  = gcol >> 2;
            #pragma unroll
            for (int q = 0; q < 2; ++q) {
                f2 v = {0.0f, 0.0f};
                if (on) {
                    v.x = xb[(c0 + 2 * q)     * MW + m];
                    v.y = xb[(c0 + 2 * q + 1) * MW + m];
                }
                S[q] = v;
            }
        }

        // ---- stage group 0 (sigmoid once); prefetch group 1 (layers 2,3) ----
        #pragma unroll
        for (int ll = 0; ll < 2; ++ll) {
            float4 sg;
            sg.x = sigm(pf[ll * 4 + 0]);
            sg.y = sigm(pf[ll * 4 + 1]);
            sg.z = sigm(pf[ll * 4 + 2]);
            sg.w = sigm(pf[ll * 4 + 3]);
            *(float4*)&twl[ll][tx][c0] = sg;
        }
        #pragma unroll
        for (int ll = 0; ll < 2; ++ll)
            #pragma unroll
            for (int k = 0; k < 4; ++k)
                pf[ll * 4 + k] = tgb[((size_t)(2 + ll) * NPOS + c0 + k) * GRID_N + gcol];
        __syncthreads();   // group-0 gates visible

        #pragma unroll
        for (int g = 0; g < 4; ++g) {          // 4 groups of 2 layers
            #pragma unroll
            for (int ll = 0; ll < 2; ++ll) {
                float tw[32];
                #pragma unroll
                for (int k = 0; k < 8; ++k) {
                    const float4 q = *(const float4*)&twl[ll][tx][4 * k];
                    tw[4 * k]     = q.x; tw[4 * k + 1] = q.y;
                    tw[4 * k + 2] = q.z; tw[4 * k + 3] = q.w;
                }
                float d0[16];
                #pragma unroll
                for (int r = 0; r < 16; ++r) d0[r] = tw[16 + r] - tw[r];

                f2 s0v[2], s1v[2], s3v[2], s4v[2];
                #pragma unroll
                for (int q = 0; q < 2; ++q) {
                    s1v[q] = shr1(S[q]);      // column n-1
                    s0v[q] = shr1(s1v[q]);    // column n-2
                    s3v[q] = shl1(S[q]);      // column n+1
                    s4v[q] = shl1(s3v[q]);    // column n+2
                }

                #pragma unroll
                for (int q = 0; q < 2; ++q) {
                    f2 u[16];
                    #pragma unroll
                    for (int r = 0; r < 16; ++r)
                        u[r] = __builtin_elementwise_fma(s0v[q], (f2)d0[r], (f2)tw[r]);
                    #pragma unroll
                    for (int r = 0; r < 8; ++r)
                        u[r] = __builtin_elementwise_fma(s1v[q], u[8 + r] - u[r], u[r]);
                    #pragma unroll
                    for (int r = 0; r < 4; ++r)
                        u[r] = __builtin_elementwise_fma(S[q], u[4 + r] - u[r], u[r]);
                    #pragma unroll
                    for (int r = 0; r < 2; ++r)
                        u[r] = __builtin_elementwise_fma(s3v[q], u[2 + r] - u[r], u[r]);
                    f2 rv = __builtin_elementwise_fma(s4v[q], u[1] - u[0], u[0]);
                    rv = __builtin_elementwise_min(__builtin_elementwise_max(rv, (f2)0.0f), (f2)1.0f);
                    S[q] = rv;
                }
            }

            if (g < 3) {
                __syncthreads();   // all waves done reading this group's gates
                #pragma unroll
                for (int ll = 0; ll < 2; ++ll) {
                    float4 sg;
                    sg.x = sigm(pf[ll * 4 + 0]);
                    sg.y = sigm(pf[ll * 4 + 1]);
                    sg.z = sigm(pf[ll * 4 + 2]);
                    sg.w = sigm(pf[ll * 4 + 3]);
                    *(float4*)&twl[ll][tx][c0] = sg;
                }
                if (g < 2) {
                    const float* tn = tgb + (size_t)(2 * g + 4) * NPOS * GRID_N;
                    #pragma unroll
                    for (int ll = 0; ll < 2; ++ll)
                        #pragma unroll
                        for (int k = 0; k < 4; ++k)
                            pf[ll * 4 + k] = tn[((size_t)ll * NPOS + c0 + k) * GRID_N + gcol];
                }
                __syncthreads();   // next group's gates visible
            }
        }

        // ---- output (identical every rep): state[:, ::4] for owned columns ----
        const int rel = tx - HALO;
        if (rel >= 0 && rel < TILE && (rel & 3) == 0) {
            const int m = (start >> 2) + (rel >> 2);
            out[(c0 + 0) * MW + m] = S[0].x;
            out[(c0 + 1) * MW + m] = S[0].y;
            out[(c0 + 2) * MW + m] = S[1].x;
            out[(c0 + 3) * MW + m] = S[1].y;
        }
    }
}

extern "C" void kernel_launch(void* const* d_in, const int* in_sizes, int n_in,
                              void* d_out, int out_size, void* d_ws, size_t ws_size,
                              hipStream_t stream) {
    const float* x  = (const float*)d_in[0];   // (32, 4096)
    const float* tg = (const float*)d_in[1];   // (8, 32, 16384)
    float* out = (float*)d_out;                // (32, 4096)
    // reps=3: pushes kernel device time past the rocprof top-5 cutoff so we
    // finally see its counters. Bench number this round is a known sacrifice.
    ASIC_44186623541335_kernel<<<GRID_N / TILE, 512, 0, stream>>>(x, tg, out, 3);
}

// Round 10
// 78.910 us; speedup vs baseline: 1.2640x; 1.2640x over previous
//
#include <hip/hip_runtime.h>

#define GRID_N 16384
#define NLAYERS 8
#define NPOS 32
#define BATCH 32
#define MW 4096          // output width
#define TILE 32
#define HALO 16          // 2 * NLAYERS
#define WBUF 64          // TILE + 2*HALO = one wave of column slots
#define ROWP 36          // gate row stride: 144B; b128 is 16-lane-phased -> 2-way max = free

typedef float f2 __attribute__((ext_vector_type(2)));

// DPP wave shifts: data from lane n-1 / n+1 (boundary lanes read 0; halo absorbs).
__device__ __forceinline__ float dpp_shr1(float v) {   // lane n <- lane n-1
    return __builtin_bit_cast(float, __builtin_amdgcn_update_dpp(
        0, __builtin_bit_cast(int, v), 0x138, 0xF, 0xF, true));
}
__device__ __forceinline__ float dpp_shl1(float v) {   // lane n <- lane n+1
    return __builtin_bit_cast(float, __builtin_amdgcn_update_dpp(
        0, __builtin_bit_cast(int, v), 0x130, 0xF, 0xF, true));
}
__device__ __forceinline__ f2 shr1(f2 v) { f2 r; r.x = dpp_shr1(v.x); r.y = dpp_shr1(v.y); return r; }
__device__ __forceinline__ f2 shl1(f2 v) { f2 r; r.x = dpp_shl1(v.x); r.y = dpp_shl1(v.y); return r; }

__device__ __forceinline__ float sigm(float v) {
    return __builtin_amdgcn_rcpf(1.0f + __expf(-v));
}

// v10: s4-FIRST tree contraction. Level 0 consumes ADJACENT gate pairs
// (tw[2r], tw[2r+1]) so each ds_read_b128 chunk feeds compute immediately ->
// fine-grained lgkmcnt interleave of the DS and VALU pipes (R9 differential
// showed they currently serialize: warm 9.9us ~= VALU 4.4 + DS 5.1 added).
// Corner index c = b0*16+b1*8+b2*4+b3*2+b4 (bi = bit for var si): contracting
// b4 first pairs adjacent corners; then b3, b2(center), b1, b0.
// Skeleton = v8: 512 blocks x 512 threads (2 blocks/CU, 4 waves/SIMD), wave =
// 4 batches x 64 slots, state in VGPRs w/ DPP exchange, gates staged 2
// layers/group (18.4 KB), rolling pf prefetch. Single launch.
__global__ __launch_bounds__(512, 4) void ASIC_44186623541335_kernel(
    const float* __restrict__ x,    // (32, 4096)
    const float* __restrict__ tg,   // (8, 32, 16384) raw logits
    float* __restrict__ out)        // (32, 4096)
{
    __shared__ __align__(16) float twl[2][WBUF][ROWP];   // 18.4 KB, gates only

    const int tid = threadIdx.x;
    const int tx  = tid & 63;        // column slot (lane)
    const int w   = tid >> 6;        // wave 0..7 -> batches 4w..4w+3, gate cols 4w..4w+3
    const int c0  = 4 * w;
    const int start = blockIdx.x * TILE;
    const int gcol  = (start - HALO + tx) & (GRID_N - 1);

    // ---- load gate logits for group 0 (layers 0,1) ----
    float pf[8];
    #pragma unroll
    for (int ll = 0; ll < 2; ++ll)
        #pragma unroll
        for (int k = 0; k < 4; ++k)
            pf[ll * 4 + k] = tg[((size_t)ll * NPOS + c0 + k) * GRID_N + gcol];

    // ---- init state IN REGISTERS: embed x at stride 4, zeros elsewhere ----
    f2 S[2];
    {
        const bool on = (gcol & 3) == 0;
        const int  m  = gcol >> 2;
        #pragma unroll
        for (int q = 0; q < 2; ++q) {
            f2 v = {0.0f, 0.0f};
            if (on) {
                v.x = x[(c0 + 2 * q)     * MW + m];
                v.y = x[(c0 + 2 * q + 1) * MW + m];
            }
            S[q] = v;
        }
    }

    // ---- stage group 0 (sigmoid once); prefetch group 1 (layers 2,3) ----
    #pragma unroll
    for (int ll = 0; ll < 2; ++ll) {
        float4 sg;
        sg.x = sigm(pf[ll * 4 + 0]);
        sg.y = sigm(pf[ll * 4 + 1]);
        sg.z = sigm(pf[ll * 4 + 2]);
        sg.w = sigm(pf[ll * 4 + 3]);
        *(float4*)&twl[ll][tx][c0] = sg;
    }
    #pragma unroll
    for (int ll = 0; ll < 2; ++ll)
        #pragma unroll
        for (int k = 0; k < 4; ++k)
            pf[ll * 4 + k] = tg[((size_t)(2 + ll) * NPOS + c0 + k) * GRID_N + gcol];
    __syncthreads();   // group-0 gates visible

    #pragma unroll
    for (int g = 0; g < 4; ++g) {          // 4 groups of 2 layers
        #pragma unroll
        for (int ll = 0; ll < 2; ++ll) {
            // neighbor states via DPP wave shifts (VALU, independent of LDS)
            f2 s0v[2], s1v[2], s3v[2], s4v[2];
            #pragma unroll
            for (int q = 0; q < 2; ++q) {
                s1v[q] = shr1(S[q]);      // column n-1
                s0v[q] = shr1(s1v[q]);    // column n-2
                s3v[q] = shl1(S[q]);      // column n+1
                s4v[q] = shl1(s3v[q]);    // column n+2
            }

            // level 0 (contract s4): chunk-wise -- each b128 feeds 4 lerps
            // per batch-pair immediately (fine-grained lgkmcnt interleave).
            f2 u0[16], u1[16];
            #pragma unroll
            for (int k = 0; k < 8; ++k) {
                const float4 t4 = *(const float4*)&twl[ll][tx][4 * k];
                const float dA = t4.y - t4.x;    // d[2k]   (batch-invariant)
                const float dB = t4.w - t4.z;    // d[2k+1]
                u0[2 * k]     = __builtin_elementwise_fma(s4v[0], (f2)dA, (f2)t4.x);
                u0[2 * k + 1] = __builtin_elementwise_fma(s4v[0], (f2)dB, (f2)t4.z);
                u1[2 * k]     = __builtin_elementwise_fma(s4v[1], (f2)dA, (f2)t4.x);
                u1[2 * k + 1] = __builtin_elementwise_fma(s4v[1], (f2)dB, (f2)t4.z);
            }

            // levels 1..4: contract s3, s2(center), s1, s0 — adjacent pairs
            #pragma unroll
            for (int q = 0; q < 2; ++q) {
                f2* u = q ? u1 : u0;
                #pragma unroll
                for (int r = 0; r < 8; ++r)
                    u[r] = __builtin_elementwise_fma(s3v[q], u[2 * r + 1] - u[2 * r], u[2 * r]);
                #pragma unroll
                for (int r = 0; r < 4; ++r)
                    u[r] = __builtin_elementwise_fma(S[q],   u[2 * r + 1] - u[2 * r], u[2 * r]);
                #pragma unroll
                for (int r = 0; r < 2; ++r)
                    u[r] = __builtin_elementwise_fma(s1v[q], u[2 * r + 1] - u[2 * r], u[2 * r]);
                f2 rv = __builtin_elementwise_fma(s0v[q], u[1] - u[0], u[0]);
                rv = __builtin_elementwise_min(__builtin_elementwise_max(rv, (f2)0.0f), (f2)1.0f);
                S[q] = rv;
            }
        }

        if (g < 3) {
            __syncthreads();   // all waves done reading this group's gates
            // stage next group (sigmoid prefetched regs)
            #pragma unroll
            for (int ll = 0; ll < 2; ++ll) {
                float4 sg;
                sg.x = sigm(pf[ll * 4 + 0]);
                sg.y = sigm(pf[ll * 4 + 1]);
                sg.z = sigm(pf[ll * 4 + 2]);
                sg.w = sigm(pf[ll * 4 + 3]);
                *(float4*)&twl[ll][tx][c0] = sg;
            }
            if (g < 2) {       // prefetch group g+2 (layers 2g+4, 2g+5)
                const float* tn = tg + (size_t)(2 * g + 4) * NPOS * GRID_N;
                #pragma unroll
                for (int ll = 0; ll < 2; ++ll)
                    #pragma unroll
                    for (int k = 0; k < 4; ++k)
                        pf[ll * 4 + k] = tn[((size_t)ll * NPOS + c0 + k) * GRID_N + gcol];
            }
            __syncthreads();   // next group's gates visible
        }
    }

    // ---- output straight from registers: state[:, ::4] for owned columns ----
    const int rel = tx - HALO;
    if (rel >= 0 && rel < TILE && (rel & 3) == 0) {
        const int m = (start >> 2) + (rel >> 2);
        out[(c0 + 0) * MW + m] = S[0].x;
        out[(c0 + 1) * MW + m] = S[0].y;
        out[(c0 + 2) * MW + m] = S[1].x;
        out[(c0 + 3) * MW + m] = S[1].y;
    }
}

extern "C" void kernel_launch(void* const* d_in, const int* in_sizes, int n_in,
                              void* d_out, int out_size, void* d_ws, size_t ws_size,
                              hipStream_t stream) {
    const float* x  = (const float*)d_in[0];   // (32, 4096)
    const float* tg = (const float*)d_in[1];   // (8, 32, 16384)
    float* out = (float*)d_out;                // (32, 4096)
    ASIC_44186623541335_kernel<<<GRID_N / TILE, 512, 0, stream>>>(x, tg, out);
}